// Round 13
// baseline (170.151 us; speedup 1.0000x reference)
//
#include <hip/hip_runtime.h>
#include <math.h>

// B=32, OBS=768, D=512, V=64
// Outputs (f32): h[32*512] | pred[32*768] | graph[64*64] | reasoning[32*512]
// 5 kernels: front -> enc2 -> gigru -> mid(dec,rs1,Cc) -> score(+rs2).
// NOTE (round 5): persistent kernel + agent-scope grid barriers = ~145us/barrier. No.
// NOTE (round 7): per-b megakernel starves CUs / re-reads weights per block. No.
// NOTE (round 9): harness fixed overhead ~74us (256MB ws re-poison fill ~44us).
// NOTE (round 10): score 4b/wave regressed: setup paid 2x. Keep 8b/wave, 256thr.
// NOTE (round 12): rolled score b-loop + per-b reduce regressed 37->44 (96 shuffles
// vs 17; dec-in-score skew). Keep R11 unrolled score + 16-way merge reduction.
// Round 13: R11 revert + BT halving on latency-bound mid-chain (front 4->2,
// enc2 2->1, gigru 2b->1b, mid 2->1): more waves = more outstanding loads.

#if __has_builtin(__builtin_amdgcn_exp2f)
#define EXP2F __builtin_amdgcn_exp2f
#else
#define EXP2F exp2f
#endif

__device__ __forceinline__ float gelu_exact(float x) {
    return 0.5f * x * (1.f + erff(x * 0.70710678118654752f));
}
__device__ __forceinline__ float sigmoid_fast(float v) {
    return __builtin_amdgcn_rcpf(1.f + EXP2F(-1.442695041f * v));
}
__device__ __forceinline__ float tanh_fast(float v) {
    return fmaf(-2.f, __builtin_amdgcn_rcpf(1.f + EXP2F(2.885390082f * v)), 1.f);
}

// Wave-tile GEMM: one wave -> out[b0..b0+BT-1][o0..o0+7].
// Merge-based reduction: 10 DS ops; lanes 0..7 hold the 8 outputs.
template<int NF4, int ACT, int BT>
__device__ __forceinline__ void wgemm(int wid,
        const float* __restrict__ A, int lda,
        const float* __restrict__ W, int ldw,
        const float* __restrict__ bias,
        float* __restrict__ out, int ldo,
        int oblocks) {
    int lane = threadIdx.x & 63;
    int oblock = wid % oblocks;
    int bgroup = wid / oblocks;
    int o0 = oblock * 8, b0 = bgroup * BT;

    float4 w[8][NF4];
#pragma unroll
    for (int r = 0; r < 8; ++r) {
        const float4* wr = reinterpret_cast<const float4*>(W + (o0 + r) * ldw);
#pragma unroll
        for (int c = 0; c < NF4; ++c) w[r][c] = wr[c * 64 + lane];
    }
    float bv = bias ? bias[o0 + (lane & 7)] : 0.f;
    bool p0 = lane & 1, p1 = lane & 2, p2 = lane & 4;

#pragma unroll
    for (int bi = 0; bi < BT; ++bi) {
        const float4* ar = reinterpret_cast<const float4*>(A + (b0 + bi) * lda);
        float4 a[NF4];
#pragma unroll
        for (int c = 0; c < NF4; ++c) a[c] = ar[c * 64 + lane];
        float s[8];
#pragma unroll
        for (int r = 0; r < 8; ++r) {
            float acc = 0.f;
#pragma unroll
            for (int c = 0; c < NF4; ++c) {
                acc = fmaf(a[c].x, w[r][c].x, acc);
                acc = fmaf(a[c].y, w[r][c].y, acc);
                acc = fmaf(a[c].z, w[r][c].z, acc);
                acc = fmaf(a[c].w, w[r][c].w, acc);
            }
            s[r] = acc;
        }
        float m[4];
#pragma unroll
        for (int k = 0; k < 4; ++k) {
            float keep = p0 ? s[2 * k + 1] : s[2 * k];
            float send = p0 ? s[2 * k] : s[2 * k + 1];
            m[k] = keep + __shfl_xor(send, 1, 64);
        }
        float n[2];
#pragma unroll
        for (int k = 0; k < 2; ++k) {
            float keep = p1 ? m[2 * k + 1] : m[2 * k];
            float send = p1 ? m[2 * k] : m[2 * k + 1];
            n[k] = keep + __shfl_xor(send, 2, 64);
        }
        float F;
        {
            float keep = p2 ? n[1] : n[0];
            float send = p2 ? n[0] : n[1];
            F = keep + __shfl_xor(send, 4, 64);
        }
        F += __shfl_xor(F, 8, 64);
        F += __shfl_xor(F, 16, 64);
        F += __shfl_xor(F, 32, 64);
        float v = F + bv;
        if (ACT) v = gelu_exact(v);
        if (lane < 8) out[(b0 + bi) * ldo + o0 + lane] = v;
    }
}

// K1: BT=2: enc1 (2048 w) + Ea (4096) + Eb (4096) + gia (3072) = 13312 w = 3328 blocks
__global__ void __launch_bounds__(256) front_kernel(
    const float* __restrict__ obs, const float* __restrict__ enc_w1,
    const float* __restrict__ enc_b1, float* __restrict__ h1,
    const float* __restrict__ embed, const float* __restrict__ sc_w1,
    const float* __restrict__ sc_b1, float* __restrict__ Ea, float* __restrict__ Eb,
    const float* __restrict__ action, const float* __restrict__ wih,
    const float* __restrict__ bih, float* __restrict__ gia) {
    int wid = blockIdx.x * 4 + (threadIdx.x >> 6);
    if (wid < 2048) {
        wgemm<3, 1, 2>(wid, obs, 768, enc_w1, 768, enc_b1, h1, 1024, 128);
    } else if (wid < 6144) {
        wgemm<2, 0, 2>(wid - 2048, embed, 512, sc_w1, 1536, sc_b1, Ea, 1024, 128);
    } else if (wid < 10240) {
        wgemm<2, 0, 2>(wid - 6144, embed, 512, sc_w1 + 512, 1536, nullptr, Eb, 1024, 128);
    } else {
        wgemm<2, 0, 2>(wid - 10240, action, 512, wih + 512, 1024, bih, gia, 1536, 192);
    }
}

// K2: z = h1 @ enc_w2^T + b2. BT=1: 64 ob x 32 bg = 2048 waves = 512 blocks
__global__ void __launch_bounds__(256) enc2_kernel(
    const float* __restrict__ h1, const float* __restrict__ enc_w2,
    const float* __restrict__ enc_b2, float* __restrict__ z) {
    int wid = blockIdx.x * 4 + (threadIdx.x >> 6);
    wgemm<4, 0, 1>(wid, h1, 1024, enc_w2, 1024, enc_b2, z, 512, 64);
}

// K3: z-half of gi + GRU. Wave = opair (6 rows, K=512) x 1 b.
// 256 opairs x 32 b = 8192 waves = 2048 blocks. h0=0 => gh = bhh.
__global__ void __launch_bounds__(256) gigru_kernel(
    const float* __restrict__ z, const float* __restrict__ wih,
    const float* __restrict__ gia, const float* __restrict__ bhh,
    const float* __restrict__ action, float* __restrict__ h, float* __restrict__ ha) {
    int wid = blockIdx.x * 4 + (threadIdx.x >> 6);
    int lane = threadIdx.x & 63;
    int opair = wid & 255;
    int b = wid >> 8;       // 0..31
    int o0 = opair * 2;

    int rows[6] = {o0, o0 + 1, 512 + o0, 513 + o0, 1024 + o0, 1025 + o0};
    float4 w[6][2];
#pragma unroll
    for (int r = 0; r < 6; ++r) {
        const float4* wr = reinterpret_cast<const float4*>(wih + rows[r] * 1024);
#pragma unroll
        for (int c = 0; c < 2; ++c) w[r][c] = wr[c * 64 + lane];
    }
    float bhr0 = bhh[o0],        bhr1 = bhh[o0 + 1];
    float bhu0 = bhh[512 + o0],  bhu1 = bhh[513 + o0];
    float bhn0 = bhh[1024 + o0], bhn1 = bhh[1025 + o0];

    const float4* ar = reinterpret_cast<const float4*>(z + b * 512);
    float4 a[2] = {ar[lane], ar[64 + lane]};
    float s[6];
#pragma unroll
    for (int r = 0; r < 6; ++r) {
        float acc = 0.f;
#pragma unroll
        for (int c = 0; c < 2; ++c) {
            acc = fmaf(a[c].x, w[r][c].x, acc);
            acc = fmaf(a[c].y, w[r][c].y, acc);
            acc = fmaf(a[c].z, w[r][c].z, acc);
            acc = fmaf(a[c].w, w[r][c].w, acc);
        }
        s[r] = acc;
    }
#pragma unroll
    for (int m = 1; m < 64; m <<= 1) {
#pragma unroll
        for (int r = 0; r < 6; ++r) s[r] += __shfl_xor(s[r], m, 64);
    }
    if (lane == 0) {
        const float* gb = gia + b * 1536;
        float r0 = sigmoid_fast(s[0] + gb[o0]        + bhr0);
        float r1 = sigmoid_fast(s[1] + gb[o0 + 1]    + bhr1);
        float u0 = sigmoid_fast(s[2] + gb[512 + o0]  + bhu0);
        float u1 = sigmoid_fast(s[3] + gb[513 + o0]  + bhu1);
        float n0 = tanh_fast(s[4] + gb[1024 + o0] + r0 * bhn0);
        float n1 = tanh_fast(s[5] + gb[1025 + o0] + r1 * bhn1);
        float hv0 = (1.f - u0) * n0;
        float hv1 = (1.f - u1) * n1;
        h[b * 512 + o0]      = hv0;
        h[b * 512 + o0 + 1]  = hv1;
        ha[b * 512 + o0]     = hv0 + action[b * 512 + o0];
        ha[b * 512 + o0 + 1] = hv1 + action[b * 512 + o0 + 1];
    }
}

// K4: BT=1: dec (96 ob) + rs1 (64) + Cc (128), x32 bg = 9216 waves = 2304 blocks
__global__ void __launch_bounds__(256) mid_kernel(
    const float* __restrict__ h, const float* __restrict__ ha,
    const float* __restrict__ dec_w, const float* __restrict__ dec_b, float* __restrict__ pred,
    const float* __restrict__ rs_w1, const float* __restrict__ rs_b1, float* __restrict__ r1,
    const float* __restrict__ sc_w1, float* __restrict__ Cc) {
    int wid = blockIdx.x * 4 + (threadIdx.x >> 6);
    if (wid < 3072) {
        wgemm<2, 0, 1>(wid, h, 512, dec_w, 512, dec_b, pred, 768, 96);
    } else if (wid < 5120) {
        wgemm<2, 1, 1>(wid - 3072, h, 512, rs_w1, 512, rs_b1, r1, 512, 64);
    } else {
        wgemm<2, 0, 1>(wid - 5120, ha, 512, sc_w1 + 1024, 1536, nullptr, Cc, 1024, 128);
    }
}

// K5: 2048 blocks x 256 thr. Blocks 0..63 also run rs2 first (256 waves, BT=8).
// Score: block=(i, j0..j0+1); wave w -> b in [8w,8w+8); lane -> d [16*lane,+16).
// gelu(x) ~= x/(1+2^(NK*x)). g-trick: tb = ta*g[e], g = 2^(NK*df) (j-pair const);
// shared rcp R = rcp(P*Q). Unrolled b-loop, persistent sA/sB, 16-way merge reduce.
__global__ void __launch_bounds__(256) score_rs2_kernel(
    const float* __restrict__ Ea, const float* __restrict__ Eb,
    const float* __restrict__ Cc, const float* __restrict__ w2,
    const float* __restrict__ b2, float* __restrict__ graph,
    const float* __restrict__ r1, const float* __restrict__ rs_w2,
    const float* __restrict__ rs_b2, float* __restrict__ reasoning) {
    int blk = blockIdx.x;
    if (blk < 64) {
        int wid = blk * 4 + (threadIdx.x >> 6);
        wgemm<2, 0, 8>(wid, r1, 512, rs_w2, 512, rs_b2, reasoning, 512, 64);
    }
    int i = blk >> 5;
    int j0 = (blk & 31) << 1;
    int lane = threadIdx.x & 63;
    int wave = threadIdx.x >> 6;
    int d0 = lane << 4;

    const float4* Ea4  = reinterpret_cast<const float4*>(Ea + i * 1024 + d0);
    const float4* Eb04 = reinterpret_cast<const float4*>(Eb + j0 * 1024 + d0);
    const float4* Eb14 = reinterpret_cast<const float4*>(Eb + (j0 + 1) * 1024 + d0);
    const float4* W4   = reinterpret_cast<const float4*>(w2 + d0);

    const float NK = -2.4554274f;  // -1.702 * log2(e)
    float basea[16], df[16], g[16], wv[16];
#pragma unroll
    for (int c = 0; c < 4; ++c) {
        float4 e  = Ea4[c];
        float4 f0 = Eb04[c];
        float4 f1 = Eb14[c];
        float4 w  = W4[c];
        basea[4 * c + 0] = e.x + f0.x; basea[4 * c + 1] = e.y + f0.y;
        basea[4 * c + 2] = e.z + f0.z; basea[4 * c + 3] = e.w + f0.w;
        df[4 * c + 0] = f1.x - f0.x; df[4 * c + 1] = f1.y - f0.y;
        df[4 * c + 2] = f1.z - f0.z; df[4 * c + 3] = f1.w - f0.w;
        wv[4 * c + 0] = w.x; wv[4 * c + 1] = w.y;
        wv[4 * c + 2] = w.z; wv[4 * c + 3] = w.w;
    }
#pragma unroll
    for (int e = 0; e < 16; ++e) g[e] = EXP2F(df[e] * NK);

    float sA[8], sB[8];
#pragma unroll
    for (int b = 0; b < 8; ++b) { sA[b] = 0.f; sB[b] = 0.f; }

    const float* ccbase = Cc + (wave * 8) * 1024 + d0;
#pragma unroll
    for (int b = 0; b < 8; ++b) {
        const float4* q4 = reinterpret_cast<const float4*>(ccbase + b * 1024);
        float4 c0 = q4[0], c1 = q4[1], c2 = q4[2], c3 = q4[3];
        float cc[16] = {c0.x, c0.y, c0.z, c0.w, c1.x, c1.y, c1.z, c1.w,
                        c2.x, c2.y, c2.z, c2.w, c3.x, c3.y, c3.z, c3.w};
#pragma unroll
        for (int e = 0; e < 16; e += 2) {
            float xa0 = cc[e] + basea[e];
            float xa1 = cc[e + 1] + basea[e + 1];
            float ta0 = EXP2F(xa0 * NK);
            float ta1 = EXP2F(xa1 * NK);
            float da0 = 1.f + ta0, da1 = 1.f + ta1;
            float numa = fmaf(xa0 * wv[e], da1, (xa1 * wv[e + 1]) * da0);
            float P = da0 * da1;

            float xb0 = xa0 + df[e];
            float xb1 = xa1 + df[e + 1];
            float tb0 = ta0 * g[e];
            float tb1 = ta1 * g[e + 1];
            float db0 = 1.f + tb0, db1 = 1.f + tb1;
            float numb = fmaf(xb0 * wv[e], db1, (xb1 * wv[e + 1]) * db0);
            float Q = db0 * db1;

            float R = __builtin_amdgcn_rcpf(P * Q);
            sA[b] = fmaf(numa * Q, R, sA[b]);
            sB[b] = fmaf(numb * P, R, sB[b]);
        }
    }

    // 16-way merge reduction: final value index = (j = lane&1, b = (lane>>1)&7)
    bool p0 = lane & 1, p1 = lane & 2, p2 = lane & 4, p3 = lane & 8;
    float m[8];
#pragma unroll
    for (int k = 0; k < 8; ++k) {
        float keep = p0 ? sB[k] : sA[k];
        float send = p0 ? sA[k] : sB[k];
        m[k] = keep + __shfl_xor(send, 1, 64);
    }
    float n[4];
#pragma unroll
    for (int k = 0; k < 4; ++k) {
        float keep = p1 ? m[2 * k + 1] : m[2 * k];
        float send = p1 ? m[2 * k] : m[2 * k + 1];
        n[k] = keep + __shfl_xor(send, 2, 64);
    }
    float o2[2];
#pragma unroll
    for (int k = 0; k < 2; ++k) {
        float keep = p2 ? n[2 * k + 1] : n[2 * k];
        float send = p2 ? n[2 * k] : n[2 * k + 1];
        o2[k] = keep + __shfl_xor(send, 4, 64);
    }
    float F;
    {
        float keep = p3 ? o2[1] : o2[0];
        float send = p3 ? o2[0] : o2[1];
        F = keep + __shfl_xor(send, 8, 64);
    }
    F += __shfl_xor(F, 16, 64);
    F += __shfl_xor(F, 32, 64);

    // sigmoid wave-wide, then sum over b (lane bits 1..3)
    float sig = sigmoid_fast(F + b2[0]);
    sig += __shfl_xor(sig, 2, 64);
    sig += __shfl_xor(sig, 4, 64);
    sig += __shfl_xor(sig, 8, 64);

    __shared__ float red[4][2];
    if (lane < 2) red[wave][lane] = sig;
    __syncthreads();
    if (threadIdx.x < 2) {
        graph[i * 64 + j0 + threadIdx.x] =
            (red[0][threadIdx.x] + red[1][threadIdx.x] +
             red[2][threadIdx.x] + red[3][threadIdx.x]) * 0.03125f;
    }
}

extern "C" void kernel_launch(void* const* d_in, const int* in_sizes, int n_in,
                              void* d_out, int out_size, void* d_ws, size_t ws_size,
                              hipStream_t stream) {
    const float* obs     = (const float*)d_in[0];
    const float* action  = (const float*)d_in[1];
    const float* embed   = (const float*)d_in[2];
    const float* sc_w1   = (const float*)d_in[3];
    const float* sc_b1   = (const float*)d_in[4];
    const float* sc_w2   = (const float*)d_in[5];
    const float* sc_b2   = (const float*)d_in[6];
    const float* enc_w1  = (const float*)d_in[7];
    const float* enc_b1  = (const float*)d_in[8];
    const float* enc_w2  = (const float*)d_in[9];
    const float* enc_b2  = (const float*)d_in[10];
    const float* gru_wih = (const float*)d_in[11];
    const float* gru_bih = (const float*)d_in[13];
    const float* gru_bhh = (const float*)d_in[14];
    const float* dec_w   = (const float*)d_in[15];
    const float* dec_b   = (const float*)d_in[16];
    const float* rs_w1   = (const float*)d_in[17];
    const float* rs_b1   = (const float*)d_in[18];
    const float* rs_w2   = (const float*)d_in[19];
    const float* rs_b2   = (const float*)d_in[20];

    float* ws = (float*)d_ws;
    float* h1  = ws + 0;        // 32x1024
    float* z   = ws + 32768;    // 32x512
    float* gia = ws + 49152;    // 32x1536
    float* ha  = ws + 98304;    // 32x512
    float* r1  = ws + 114688;   // 32x512
    float* Cc  = ws + 131072;   // 32x1024
    float* Ea  = ws + 163840;   // 64x1024
    float* Eb  = ws + 229376;   // 64x1024

    float* h_out     = (float*)d_out;
    float* pred      = h_out + 16384;
    float* graph     = h_out + 40960;
    float* reasoning = h_out + 45056;

    front_kernel<<<3328, 256, 0, stream>>>(obs, enc_w1, enc_b1, h1,
                                           embed, sc_w1, sc_b1, Ea, Eb,
                                           action, gru_wih, gru_bih, gia);
    enc2_kernel<<<512, 256, 0, stream>>>(h1, enc_w2, enc_b2, z);
    gigru_kernel<<<2048, 256, 0, stream>>>(z, gru_wih, gia, gru_bhh, action, h_out, ha);
    mid_kernel<<<2304, 256, 0, stream>>>(h_out, ha, dec_w, dec_b, pred,
                                         rs_w1, rs_b1, r1, sc_w1, Cc);
    score_rs2_kernel<<<2048, 256, 0, stream>>>(Ea, Eb, Cc, sc_w2, sc_b2, graph,
                                               r1, rs_w2, rs_b2, reasoning);
}

// Round 14
// 164.177 us; speedup vs baseline: 1.0364x; 1.0364x over previous
//
#include <hip/hip_runtime.h>
#include <math.h>

// B=32, OBS=768, D=512, V=64
// Outputs (f32): h[32*512] | pred[32*768] | graph[64*64] | reasoning[32*512]
// 5 kernels: front -> enc2 -> gigru -> mid(dec,rs1,Cc) -> score(+rs2). [R11 config]
// NOTE (round 5): persistent kernel + agent-scope grid barriers = ~145us/barrier. No.
// NOTE (round 7): per-b megakernel starves CUs / re-reads weights per block. No.
// NOTE (round 9): harness fixed overhead ~74us (256MB ws re-poison fill ~44us).
// NOTE (round 10): score 4b/wave regressed: setup paid 2x. Keep 8b/wave, 256thr.
// NOTE (round 12): rolled score b-loop regressed (per-b reduce = 96 shuffles). No.
// NOTE (round 13): BT=1 mid-chain neutral-negative: stages at dispatch+latency floor.
// Round 14: exact R11 revert + score inner loop in f32x2 (ext_vector) to coax
// v_pk_{add,mul}_f32 — halves issue slots + code bytes on the packable ~half.

#if __has_builtin(__builtin_amdgcn_exp2f)
#define EXP2F __builtin_amdgcn_exp2f
#else
#define EXP2F exp2f
#endif

typedef float f32x2 __attribute__((ext_vector_type(2)));

__device__ __forceinline__ float gelu_exact(float x) {
    return 0.5f * x * (1.f + erff(x * 0.70710678118654752f));
}
__device__ __forceinline__ float sigmoid_fast(float v) {
    return __builtin_amdgcn_rcpf(1.f + EXP2F(-1.442695041f * v));
}
__device__ __forceinline__ float tanh_fast(float v) {
    return fmaf(-2.f, __builtin_amdgcn_rcpf(1.f + EXP2F(2.885390082f * v)), 1.f);
}

// Wave-tile GEMM: one wave -> out[b0..b0+BT-1][o0..o0+7].
// Merge-based reduction: 10 DS ops; lanes 0..7 hold the 8 outputs.
template<int NF4, int ACT, int BT>
__device__ __forceinline__ void wgemm(int wid,
        const float* __restrict__ A, int lda,
        const float* __restrict__ W, int ldw,
        const float* __restrict__ bias,
        float* __restrict__ out, int ldo,
        int oblocks) {
    int lane = threadIdx.x & 63;
    int oblock = wid % oblocks;
    int bgroup = wid / oblocks;
    int o0 = oblock * 8, b0 = bgroup * BT;

    float4 w[8][NF4];
#pragma unroll
    for (int r = 0; r < 8; ++r) {
        const float4* wr = reinterpret_cast<const float4*>(W + (o0 + r) * ldw);
#pragma unroll
        for (int c = 0; c < NF4; ++c) w[r][c] = wr[c * 64 + lane];
    }
    float bv = bias ? bias[o0 + (lane & 7)] : 0.f;
    bool p0 = lane & 1, p1 = lane & 2, p2 = lane & 4;

#pragma unroll
    for (int bi = 0; bi < BT; ++bi) {
        const float4* ar = reinterpret_cast<const float4*>(A + (b0 + bi) * lda);
        float4 a[NF4];
#pragma unroll
        for (int c = 0; c < NF4; ++c) a[c] = ar[c * 64 + lane];
        float s[8];
#pragma unroll
        for (int r = 0; r < 8; ++r) {
            float acc = 0.f;
#pragma unroll
            for (int c = 0; c < NF4; ++c) {
                acc = fmaf(a[c].x, w[r][c].x, acc);
                acc = fmaf(a[c].y, w[r][c].y, acc);
                acc = fmaf(a[c].z, w[r][c].z, acc);
                acc = fmaf(a[c].w, w[r][c].w, acc);
            }
            s[r] = acc;
        }
        float m[4];
#pragma unroll
        for (int k = 0; k < 4; ++k) {
            float keep = p0 ? s[2 * k + 1] : s[2 * k];
            float send = p0 ? s[2 * k] : s[2 * k + 1];
            m[k] = keep + __shfl_xor(send, 1, 64);
        }
        float n[2];
#pragma unroll
        for (int k = 0; k < 2; ++k) {
            float keep = p1 ? m[2 * k + 1] : m[2 * k];
            float send = p1 ? m[2 * k] : m[2 * k + 1];
            n[k] = keep + __shfl_xor(send, 2, 64);
        }
        float F;
        {
            float keep = p2 ? n[1] : n[0];
            float send = p2 ? n[0] : n[1];
            F = keep + __shfl_xor(send, 4, 64);
        }
        F += __shfl_xor(F, 8, 64);
        F += __shfl_xor(F, 16, 64);
        F += __shfl_xor(F, 32, 64);
        float v = F + bv;
        if (ACT) v = gelu_exact(v);
        if (lane < 8) out[(b0 + bi) * ldo + o0 + lane] = v;
    }
}

// K1: BT=4: enc1 (1024 w) + Ea (2048) + Eb (2048) + gia (1536) = 6656 w = 1664 blocks
__global__ void __launch_bounds__(256) front_kernel(
    const float* __restrict__ obs, const float* __restrict__ enc_w1,
    const float* __restrict__ enc_b1, float* __restrict__ h1,
    const float* __restrict__ embed, const float* __restrict__ sc_w1,
    const float* __restrict__ sc_b1, float* __restrict__ Ea, float* __restrict__ Eb,
    const float* __restrict__ action, const float* __restrict__ wih,
    const float* __restrict__ bih, float* __restrict__ gia) {
    int wid = blockIdx.x * 4 + (threadIdx.x >> 6);
    if (wid < 1024) {
        wgemm<3, 1, 4>(wid, obs, 768, enc_w1, 768, enc_b1, h1, 1024, 128);
    } else if (wid < 3072) {
        wgemm<2, 0, 4>(wid - 1024, embed, 512, sc_w1, 1536, sc_b1, Ea, 1024, 128);
    } else if (wid < 5120) {
        wgemm<2, 0, 4>(wid - 3072, embed, 512, sc_w1 + 512, 1536, nullptr, Eb, 1024, 128);
    } else {
        wgemm<2, 0, 4>(wid - 5120, action, 512, wih + 512, 1024, bih, gia, 1536, 192);
    }
}

// K2: z = h1 @ enc_w2^T + b2. BT=2: 64 ob x 16 bg = 1024 waves = 256 blocks
__global__ void __launch_bounds__(256) enc2_kernel(
    const float* __restrict__ h1, const float* __restrict__ enc_w2,
    const float* __restrict__ enc_b2, float* __restrict__ z) {
    int wid = blockIdx.x * 4 + (threadIdx.x >> 6);
    wgemm<4, 0, 2>(wid, h1, 1024, enc_w2, 1024, enc_b2, z, 512, 64);
}

// K3: z-half of gi + GRU. Wave = opair (6 rows, K=512) x 2 b.
// 256 opairs x 16 bgroups = 4096 waves = 1024 blocks. h0=0 => gh = bhh.
__global__ void __launch_bounds__(256) gigru_kernel(
    const float* __restrict__ z, const float* __restrict__ wih,
    const float* __restrict__ gia, const float* __restrict__ bhh,
    const float* __restrict__ action, float* __restrict__ h, float* __restrict__ ha) {
    int wid = blockIdx.x * 4 + (threadIdx.x >> 6);
    int lane = threadIdx.x & 63;
    int opair = wid & 255;
    int bg = wid >> 8;
    int o0 = opair * 2, b0 = bg * 2;

    int rows[6] = {o0, o0 + 1, 512 + o0, 513 + o0, 1024 + o0, 1025 + o0};
    float4 w[6][2];
#pragma unroll
    for (int r = 0; r < 6; ++r) {
        const float4* wr = reinterpret_cast<const float4*>(wih + rows[r] * 1024);
#pragma unroll
        for (int c = 0; c < 2; ++c) w[r][c] = wr[c * 64 + lane];
    }
    float bhr0 = bhh[o0],        bhr1 = bhh[o0 + 1];
    float bhu0 = bhh[512 + o0],  bhu1 = bhh[513 + o0];
    float bhn0 = bhh[1024 + o0], bhn1 = bhh[1025 + o0];

#pragma unroll
    for (int bi = 0; bi < 2; ++bi) {
        int b = b0 + bi;
        const float4* ar = reinterpret_cast<const float4*>(z + b * 512);
        float4 a[2] = {ar[lane], ar[64 + lane]};
        float s[6];
#pragma unroll
        for (int r = 0; r < 6; ++r) {
            float acc = 0.f;
#pragma unroll
            for (int c = 0; c < 2; ++c) {
                acc = fmaf(a[c].x, w[r][c].x, acc);
                acc = fmaf(a[c].y, w[r][c].y, acc);
                acc = fmaf(a[c].z, w[r][c].z, acc);
                acc = fmaf(a[c].w, w[r][c].w, acc);
            }
            s[r] = acc;
        }
#pragma unroll
        for (int m = 1; m < 64; m <<= 1) {
#pragma unroll
            for (int r = 0; r < 6; ++r) s[r] += __shfl_xor(s[r], m, 64);
        }
        if (lane == 0) {
            const float* gb = gia + b * 1536;
            float r0 = sigmoid_fast(s[0] + gb[o0]        + bhr0);
            float r1 = sigmoid_fast(s[1] + gb[o0 + 1]    + bhr1);
            float u0 = sigmoid_fast(s[2] + gb[512 + o0]  + bhu0);
            float u1 = sigmoid_fast(s[3] + gb[513 + o0]  + bhu1);
            float n0 = tanh_fast(s[4] + gb[1024 + o0] + r0 * bhn0);
            float n1 = tanh_fast(s[5] + gb[1025 + o0] + r1 * bhn1);
            float hv0 = (1.f - u0) * n0;
            float hv1 = (1.f - u1) * n1;
            h[b * 512 + o0]      = hv0;
            h[b * 512 + o0 + 1]  = hv1;
            ha[b * 512 + o0]     = hv0 + action[b * 512 + o0];
            ha[b * 512 + o0 + 1] = hv1 + action[b * 512 + o0 + 1];
        }
    }
}

// K4: BT=2: dec (96 ob) + rs1 (64) + Cc (128), x16 bg = 4608 waves = 1152 blocks
__global__ void __launch_bounds__(256) mid_kernel(
    const float* __restrict__ h, const float* __restrict__ ha,
    const float* __restrict__ dec_w, const float* __restrict__ dec_b, float* __restrict__ pred,
    const float* __restrict__ rs_w1, const float* __restrict__ rs_b1, float* __restrict__ r1,
    const float* __restrict__ sc_w1, float* __restrict__ Cc) {
    int wid = blockIdx.x * 4 + (threadIdx.x >> 6);
    if (wid < 1536) {
        wgemm<2, 0, 2>(wid, h, 512, dec_w, 512, dec_b, pred, 768, 96);
    } else if (wid < 2560) {
        wgemm<2, 1, 2>(wid - 1536, h, 512, rs_w1, 512, rs_b1, r1, 512, 64);
    } else {
        wgemm<2, 0, 2>(wid - 2560, ha, 512, sc_w1 + 1024, 1536, nullptr, Cc, 1024, 128);
    }
}

// K5: 2048 blocks x 256 thr. Blocks 0..63 also run rs2 first (256 waves, BT=8).
// Score: block=(i, j0..j0+1); wave w -> b in [8w,8w+8); lane -> d [16*lane,+16).
// gelu(x) ~= x/(1+2^(NK*x)). g-trick: tb = ta*g[e] (g j-pair const); shared rcp
// R = rcp(P*Q). Unrolled b-loop, persistent sA/sB, 16-way merge reduce.
// Packable half of the iter in f32x2 to coax v_pk_{add,mul}_f32.
__global__ void __launch_bounds__(256) score_rs2_kernel(
    const float* __restrict__ Ea, const float* __restrict__ Eb,
    const float* __restrict__ Cc, const float* __restrict__ w2,
    const float* __restrict__ b2, float* __restrict__ graph,
    const float* __restrict__ r1, const float* __restrict__ rs_w2,
    const float* __restrict__ rs_b2, float* __restrict__ reasoning) {
    int blk = blockIdx.x;
    if (blk < 64) {
        int wid = blk * 4 + (threadIdx.x >> 6);
        wgemm<2, 0, 8>(wid, r1, 512, rs_w2, 512, rs_b2, reasoning, 512, 64);
    }
    int i = blk >> 5;
    int j0 = (blk & 31) << 1;
    int lane = threadIdx.x & 63;
    int wave = threadIdx.x >> 6;
    int d0 = lane << 4;

    const float4* Ea4  = reinterpret_cast<const float4*>(Ea + i * 1024 + d0);
    const float4* Eb04 = reinterpret_cast<const float4*>(Eb + j0 * 1024 + d0);
    const float4* Eb14 = reinterpret_cast<const float4*>(Eb + (j0 + 1) * 1024 + d0);
    const float4* W4   = reinterpret_cast<const float4*>(w2 + d0);

    const float NK = -2.4554274f;  // -1.702 * log2(e)
    const f32x2 nk2  = {NK, NK};
    const f32x2 one2 = {1.f, 1.f};
    f32x2 base2[8], df2[8], g2[8], wv2[8];
#pragma unroll
    for (int c = 0; c < 4; ++c) {
        float4 e  = Ea4[c];
        float4 f0 = Eb04[c];
        float4 f1 = Eb14[c];
        float4 w  = W4[c];
        base2[2 * c]     = f32x2{e.x + f0.x, e.y + f0.y};
        base2[2 * c + 1] = f32x2{e.z + f0.z, e.w + f0.w};
        df2[2 * c]       = f32x2{f1.x - f0.x, f1.y - f0.y};
        df2[2 * c + 1]   = f32x2{f1.z - f0.z, f1.w - f0.w};
        wv2[2 * c]       = f32x2{w.x, w.y};
        wv2[2 * c + 1]   = f32x2{w.z, w.w};
    }
#pragma unroll
    for (int e = 0; e < 8; ++e) {
        f32x2 a = df2[e] * nk2;
        g2[e].x = EXP2F(a.x);
        g2[e].y = EXP2F(a.y);
    }

    float sA[8], sB[8];
#pragma unroll
    for (int b = 0; b < 8; ++b) { sA[b] = 0.f; sB[b] = 0.f; }

    const float* ccbase = Cc + (wave * 8) * 1024 + d0;
#pragma unroll
    for (int b = 0; b < 8; ++b) {
        const float4* q4 = reinterpret_cast<const float4*>(ccbase + b * 1024);
        float4 c0 = q4[0], c1 = q4[1], c2 = q4[2], c3 = q4[3];
        f32x2 cc2[8] = {f32x2{c0.x, c0.y}, f32x2{c0.z, c0.w},
                        f32x2{c1.x, c1.y}, f32x2{c1.z, c1.w},
                        f32x2{c2.x, c2.y}, f32x2{c2.z, c2.w},
                        f32x2{c3.x, c3.y}, f32x2{c3.z, c3.w}};
#pragma unroll
        for (int e = 0; e < 8; ++e) {
            f32x2 xa  = cc2[e] + base2[e];      // pk_add
            f32x2 arg = xa * nk2;               // pk_mul
            f32x2 ta;
            ta.x = EXP2F(arg.x);
            ta.y = EXP2F(arg.y);
            f32x2 da  = ta + one2;              // pk_add
            f32x2 xb  = xa + df2[e];            // pk_add
            f32x2 tb  = ta * g2[e];             // pk_mul
            f32x2 db  = tb + one2;              // pk_add
            f32x2 xaw = xa * wv2[e];            // pk_mul
            f32x2 xbw = xb * wv2[e];            // pk_mul
            float numa = fmaf(xaw.x, da.y, xaw.y * da.x);
            float P = da.x * da.y;
            float numb = fmaf(xbw.x, db.y, xbw.y * db.x);
            float Q = db.x * db.y;
            float R = __builtin_amdgcn_rcpf(P * Q);
            sA[b] = fmaf(numa * Q, R, sA[b]);
            sB[b] = fmaf(numb * P, R, sB[b]);
        }
    }

    // 16-way merge reduction: final value index = (j = lane&1, b = (lane>>1)&7)
    bool p0 = lane & 1, p1 = lane & 2, p2 = lane & 4, p3 = lane & 8;
    float m[8];
#pragma unroll
    for (int k = 0; k < 8; ++k) {
        float keep = p0 ? sB[k] : sA[k];
        float send = p0 ? sA[k] : sB[k];
        m[k] = keep + __shfl_xor(send, 1, 64);
    }
    float n[4];
#pragma unroll
    for (int k = 0; k < 4; ++k) {
        float keep = p1 ? m[2 * k + 1] : m[2 * k];
        float send = p1 ? m[2 * k] : m[2 * k + 1];
        n[k] = keep + __shfl_xor(send, 2, 64);
    }
    float o2[2];
#pragma unroll
    for (int k = 0; k < 2; ++k) {
        float keep = p2 ? n[2 * k + 1] : n[2 * k];
        float send = p2 ? n[2 * k] : n[2 * k + 1];
        o2[k] = keep + __shfl_xor(send, 4, 64);
    }
    float F;
    {
        float keep = p3 ? o2[1] : o2[0];
        float send = p3 ? o2[0] : o2[1];
        F = keep + __shfl_xor(send, 8, 64);
    }
    F += __shfl_xor(F, 16, 64);
    F += __shfl_xor(F, 32, 64);

    // sigmoid wave-wide, then sum over b (lane bits 1..3)
    float sig = sigmoid_fast(F + b2[0]);
    sig += __shfl_xor(sig, 2, 64);
    sig += __shfl_xor(sig, 4, 64);
    sig += __shfl_xor(sig, 8, 64);

    __shared__ float red[4][2];
    if (lane < 2) red[wave][lane] = sig;
    __syncthreads();
    if (threadIdx.x < 2) {
        graph[i * 64 + j0 + threadIdx.x] =
            (red[0][threadIdx.x] + red[1][threadIdx.x] +
             red[2][threadIdx.x] + red[3][threadIdx.x]) * 0.03125f;
    }
}

extern "C" void kernel_launch(void* const* d_in, const int* in_sizes, int n_in,
                              void* d_out, int out_size, void* d_ws, size_t ws_size,
                              hipStream_t stream) {
    const float* obs     = (const float*)d_in[0];
    const float* action  = (const float*)d_in[1];
    const float* embed   = (const float*)d_in[2];
    const float* sc_w1   = (const float*)d_in[3];
    const float* sc_b1   = (const float*)d_in[4];
    const float* sc_w2   = (const float*)d_in[5];
    const float* sc_b2   = (const float*)d_in[6];
    const float* enc_w1  = (const float*)d_in[7];
    const float* enc_b1  = (const float*)d_in[8];
    const float* enc_w2  = (const float*)d_in[9];
    const float* enc_b2  = (const float*)d_in[10];
    const float* gru_wih = (const float*)d_in[11];
    const float* gru_bih = (const float*)d_in[13];
    const float* gru_bhh = (const float*)d_in[14];
    const float* dec_w   = (const float*)d_in[15];
    const float* dec_b   = (const float*)d_in[16];
    const float* rs_w1   = (const float*)d_in[17];
    const float* rs_b1   = (const float*)d_in[18];
    const float* rs_w2   = (const float*)d_in[19];
    const float* rs_b2   = (const float*)d_in[20];

    float* ws = (float*)d_ws;
    float* h1  = ws + 0;        // 32x1024
    float* z   = ws + 32768;    // 32x512
    float* gia = ws + 49152;    // 32x1536
    float* ha  = ws + 98304;    // 32x512
    float* r1  = ws + 114688;   // 32x512
    float* Cc  = ws + 131072;   // 32x1024
    float* Ea  = ws + 163840;   // 64x1024
    float* Eb  = ws + 229376;   // 64x1024

    float* h_out     = (float*)d_out;
    float* pred      = h_out + 16384;
    float* graph     = h_out + 40960;
    float* reasoning = h_out + 45056;

    front_kernel<<<1664, 256, 0, stream>>>(obs, enc_w1, enc_b1, h1,
                                           embed, sc_w1, sc_b1, Ea, Eb,
                                           action, gru_wih, gru_bih, gia);
    enc2_kernel<<<256, 256, 0, stream>>>(h1, enc_w2, enc_b2, z);
    gigru_kernel<<<1024, 256, 0, stream>>>(z, gru_wih, gia, gru_bhh, action, h_out, ha);
    mid_kernel<<<1152, 256, 0, stream>>>(h_out, ha, dec_w, dec_b, pred,
                                         rs_w1, rs_b1, r1, sc_w1, Cc);
    score_rs2_kernel<<<2048, 256, 0, stream>>>(Ea, Eb, Cc, sc_w2, sc_b2, graph,
                                               r1, rs_w2, rs_b2, reasoning);
}

// Round 15
// 163.719 us; speedup vs baseline: 1.0393x; 1.0028x over previous
//
#include <hip/hip_runtime.h>
#include <math.h>

// B=32, OBS=768, D=512, V=64
// Outputs (f32): h[32*512] | pred[32*768] | graph[64*64] | reasoning[32*512]
// 5 kernels: front -> enc2 -> gigru -> mid(dec,rs1,Cc) -> score(+rs2). [R11/R14 config]
// NOTE (round 5): persistent kernel + agent-scope grid barriers = ~145us/barrier. No.
// NOTE (round 7): per-b megakernel starves CUs / re-reads weights per block. No.
// NOTE (round 9): harness fixed overhead ~74us (256MB ws re-poison fill ~44us).
// NOTE (round 10): score 4b/wave regressed: setup paid 2x. Keep 8b/wave, 256thr.
// NOTE (round 12): rolled score b-loop regressed (per-b reduce = 96 shuffles). No.
// NOTE (round 13): BT=1 mid-chain neutral-negative: stages at dispatch+latency floor.
// Round 15: score micro-fusions: db = pk_fma(ta,g,1); xb eliminated via
// dfw = df*wv precompute (xbw = xaw + dfw). 8 pk -> 6 pk per e-iter.

#if __has_builtin(__builtin_amdgcn_exp2f)
#define EXP2F __builtin_amdgcn_exp2f
#else
#define EXP2F exp2f
#endif

typedef float f32x2 __attribute__((ext_vector_type(2)));

__device__ __forceinline__ float gelu_exact(float x) {
    return 0.5f * x * (1.f + erff(x * 0.70710678118654752f));
}
__device__ __forceinline__ float sigmoid_fast(float v) {
    return __builtin_amdgcn_rcpf(1.f + EXP2F(-1.442695041f * v));
}
__device__ __forceinline__ float tanh_fast(float v) {
    return fmaf(-2.f, __builtin_amdgcn_rcpf(1.f + EXP2F(2.885390082f * v)), 1.f);
}

// Wave-tile GEMM: one wave -> out[b0..b0+BT-1][o0..o0+7].
// Merge-based reduction: 10 DS ops; lanes 0..7 hold the 8 outputs.
template<int NF4, int ACT, int BT>
__device__ __forceinline__ void wgemm(int wid,
        const float* __restrict__ A, int lda,
        const float* __restrict__ W, int ldw,
        const float* __restrict__ bias,
        float* __restrict__ out, int ldo,
        int oblocks) {
    int lane = threadIdx.x & 63;
    int oblock = wid % oblocks;
    int bgroup = wid / oblocks;
    int o0 = oblock * 8, b0 = bgroup * BT;

    float4 w[8][NF4];
#pragma unroll
    for (int r = 0; r < 8; ++r) {
        const float4* wr = reinterpret_cast<const float4*>(W + (o0 + r) * ldw);
#pragma unroll
        for (int c = 0; c < NF4; ++c) w[r][c] = wr[c * 64 + lane];
    }
    float bv = bias ? bias[o0 + (lane & 7)] : 0.f;
    bool p0 = lane & 1, p1 = lane & 2, p2 = lane & 4;

#pragma unroll
    for (int bi = 0; bi < BT; ++bi) {
        const float4* ar = reinterpret_cast<const float4*>(A + (b0 + bi) * lda);
        float4 a[NF4];
#pragma unroll
        for (int c = 0; c < NF4; ++c) a[c] = ar[c * 64 + lane];
        float s[8];
#pragma unroll
        for (int r = 0; r < 8; ++r) {
            float acc = 0.f;
#pragma unroll
            for (int c = 0; c < NF4; ++c) {
                acc = fmaf(a[c].x, w[r][c].x, acc);
                acc = fmaf(a[c].y, w[r][c].y, acc);
                acc = fmaf(a[c].z, w[r][c].z, acc);
                acc = fmaf(a[c].w, w[r][c].w, acc);
            }
            s[r] = acc;
        }
        float m[4];
#pragma unroll
        for (int k = 0; k < 4; ++k) {
            float keep = p0 ? s[2 * k + 1] : s[2 * k];
            float send = p0 ? s[2 * k] : s[2 * k + 1];
            m[k] = keep + __shfl_xor(send, 1, 64);
        }
        float n[2];
#pragma unroll
        for (int k = 0; k < 2; ++k) {
            float keep = p1 ? m[2 * k + 1] : m[2 * k];
            float send = p1 ? m[2 * k] : m[2 * k + 1];
            n[k] = keep + __shfl_xor(send, 2, 64);
        }
        float F;
        {
            float keep = p2 ? n[1] : n[0];
            float send = p2 ? n[0] : n[1];
            F = keep + __shfl_xor(send, 4, 64);
        }
        F += __shfl_xor(F, 8, 64);
        F += __shfl_xor(F, 16, 64);
        F += __shfl_xor(F, 32, 64);
        float v = F + bv;
        if (ACT) v = gelu_exact(v);
        if (lane < 8) out[(b0 + bi) * ldo + o0 + lane] = v;
    }
}

// K1: BT=4: enc1 (1024 w) + Ea (2048) + Eb (2048) + gia (1536) = 6656 w = 1664 blocks
__global__ void __launch_bounds__(256) front_kernel(
    const float* __restrict__ obs, const float* __restrict__ enc_w1,
    const float* __restrict__ enc_b1, float* __restrict__ h1,
    const float* __restrict__ embed, const float* __restrict__ sc_w1,
    const float* __restrict__ sc_b1, float* __restrict__ Ea, float* __restrict__ Eb,
    const float* __restrict__ action, const float* __restrict__ wih,
    const float* __restrict__ bih, float* __restrict__ gia) {
    int wid = blockIdx.x * 4 + (threadIdx.x >> 6);
    if (wid < 1024) {
        wgemm<3, 1, 4>(wid, obs, 768, enc_w1, 768, enc_b1, h1, 1024, 128);
    } else if (wid < 3072) {
        wgemm<2, 0, 4>(wid - 1024, embed, 512, sc_w1, 1536, sc_b1, Ea, 1024, 128);
    } else if (wid < 5120) {
        wgemm<2, 0, 4>(wid - 3072, embed, 512, sc_w1 + 512, 1536, nullptr, Eb, 1024, 128);
    } else {
        wgemm<2, 0, 4>(wid - 5120, action, 512, wih + 512, 1024, bih, gia, 1536, 192);
    }
}

// K2: z = h1 @ enc_w2^T + b2. BT=2: 64 ob x 16 bg = 1024 waves = 256 blocks
__global__ void __launch_bounds__(256) enc2_kernel(
    const float* __restrict__ h1, const float* __restrict__ enc_w2,
    const float* __restrict__ enc_b2, float* __restrict__ z) {
    int wid = blockIdx.x * 4 + (threadIdx.x >> 6);
    wgemm<4, 0, 2>(wid, h1, 1024, enc_w2, 1024, enc_b2, z, 512, 64);
}

// K3: z-half of gi + GRU. Wave = opair (6 rows, K=512) x 2 b.
// 256 opairs x 16 bgroups = 4096 waves = 1024 blocks. h0=0 => gh = bhh.
__global__ void __launch_bounds__(256) gigru_kernel(
    const float* __restrict__ z, const float* __restrict__ wih,
    const float* __restrict__ gia, const float* __restrict__ bhh,
    const float* __restrict__ action, float* __restrict__ h, float* __restrict__ ha) {
    int wid = blockIdx.x * 4 + (threadIdx.x >> 6);
    int lane = threadIdx.x & 63;
    int opair = wid & 255;
    int bg = wid >> 8;
    int o0 = opair * 2, b0 = bg * 2;

    int rows[6] = {o0, o0 + 1, 512 + o0, 513 + o0, 1024 + o0, 1025 + o0};
    float4 w[6][2];
#pragma unroll
    for (int r = 0; r < 6; ++r) {
        const float4* wr = reinterpret_cast<const float4*>(wih + rows[r] * 1024);
#pragma unroll
        for (int c = 0; c < 2; ++c) w[r][c] = wr[c * 64 + lane];
    }
    float bhr0 = bhh[o0],        bhr1 = bhh[o0 + 1];
    float bhu0 = bhh[512 + o0],  bhu1 = bhh[513 + o0];
    float bhn0 = bhh[1024 + o0], bhn1 = bhh[1025 + o0];

#pragma unroll
    for (int bi = 0; bi < 2; ++bi) {
        int b = b0 + bi;
        const float4* ar = reinterpret_cast<const float4*>(z + b * 512);
        float4 a[2] = {ar[lane], ar[64 + lane]};
        float s[6];
#pragma unroll
        for (int r = 0; r < 6; ++r) {
            float acc = 0.f;
#pragma unroll
            for (int c = 0; c < 2; ++c) {
                acc = fmaf(a[c].x, w[r][c].x, acc);
                acc = fmaf(a[c].y, w[r][c].y, acc);
                acc = fmaf(a[c].z, w[r][c].z, acc);
                acc = fmaf(a[c].w, w[r][c].w, acc);
            }
            s[r] = acc;
        }
#pragma unroll
        for (int m = 1; m < 64; m <<= 1) {
#pragma unroll
            for (int r = 0; r < 6; ++r) s[r] += __shfl_xor(s[r], m, 64);
        }
        if (lane == 0) {
            const float* gb = gia + b * 1536;
            float r0 = sigmoid_fast(s[0] + gb[o0]        + bhr0);
            float r1 = sigmoid_fast(s[1] + gb[o0 + 1]    + bhr1);
            float u0 = sigmoid_fast(s[2] + gb[512 + o0]  + bhu0);
            float u1 = sigmoid_fast(s[3] + gb[513 + o0]  + bhu1);
            float n0 = tanh_fast(s[4] + gb[1024 + o0] + r0 * bhn0);
            float n1 = tanh_fast(s[5] + gb[1025 + o0] + r1 * bhn1);
            float hv0 = (1.f - u0) * n0;
            float hv1 = (1.f - u1) * n1;
            h[b * 512 + o0]      = hv0;
            h[b * 512 + o0 + 1]  = hv1;
            ha[b * 512 + o0]     = hv0 + action[b * 512 + o0];
            ha[b * 512 + o0 + 1] = hv1 + action[b * 512 + o0 + 1];
        }
    }
}

// K4: BT=2: dec (96 ob) + rs1 (64) + Cc (128), x16 bg = 4608 waves = 1152 blocks
__global__ void __launch_bounds__(256) mid_kernel(
    const float* __restrict__ h, const float* __restrict__ ha,
    const float* __restrict__ dec_w, const float* __restrict__ dec_b, float* __restrict__ pred,
    const float* __restrict__ rs_w1, const float* __restrict__ rs_b1, float* __restrict__ r1,
    const float* __restrict__ sc_w1, float* __restrict__ Cc) {
    int wid = blockIdx.x * 4 + (threadIdx.x >> 6);
    if (wid < 1536) {
        wgemm<2, 0, 2>(wid, h, 512, dec_w, 512, dec_b, pred, 768, 96);
    } else if (wid < 2560) {
        wgemm<2, 1, 2>(wid - 1536, h, 512, rs_w1, 512, rs_b1, r1, 512, 64);
    } else {
        wgemm<2, 0, 2>(wid - 2560, ha, 512, sc_w1 + 1024, 1536, nullptr, Cc, 1024, 128);
    }
}

// K5: 2048 blocks x 256 thr. Blocks 0..63 also run rs2 first (256 waves, BT=8).
// Score: block=(i, j0..j0+1); wave w -> b in [8w,8w+8); lane -> d [16*lane,+16).
// gelu(x) ~= x/(1+2^(NK*x)). g-trick (tb = ta*g), shared rcp R = rcp(P*Q),
// unrolled b-loop, persistent sA/sB, 16-way merge reduce, f32x2 pk ops.
// R15 fusions: db = pk_fma(ta,g,1); xbw = xaw + dfw (dfw = df*wv precomputed).
__global__ void __launch_bounds__(256) score_rs2_kernel(
    const float* __restrict__ Ea, const float* __restrict__ Eb,
    const float* __restrict__ Cc, const float* __restrict__ w2,
    const float* __restrict__ b2, float* __restrict__ graph,
    const float* __restrict__ r1, const float* __restrict__ rs_w2,
    const float* __restrict__ rs_b2, float* __restrict__ reasoning) {
    int blk = blockIdx.x;
    if (blk < 64) {
        int wid = blk * 4 + (threadIdx.x >> 6);
        wgemm<2, 0, 8>(wid, r1, 512, rs_w2, 512, rs_b2, reasoning, 512, 64);
    }
    int i = blk >> 5;
    int j0 = (blk & 31) << 1;
    int lane = threadIdx.x & 63;
    int wave = threadIdx.x >> 6;
    int d0 = lane << 4;

    const float4* Ea4  = reinterpret_cast<const float4*>(Ea + i * 1024 + d0);
    const float4* Eb04 = reinterpret_cast<const float4*>(Eb + j0 * 1024 + d0);
    const float4* Eb14 = reinterpret_cast<const float4*>(Eb + (j0 + 1) * 1024 + d0);
    const float4* W4   = reinterpret_cast<const float4*>(w2 + d0);

    const float NK = -2.4554274f;  // -1.702 * log2(e)
    const f32x2 nk2  = {NK, NK};
    const f32x2 one2 = {1.f, 1.f};
    f32x2 base2[8], dfw2[8], g2[8], wv2[8];
#pragma unroll
    for (int c = 0; c < 4; ++c) {
        float4 e  = Ea4[c];
        float4 f0 = Eb04[c];
        float4 f1 = Eb14[c];
        float4 w  = W4[c];
        base2[2 * c]     = f32x2{e.x + f0.x, e.y + f0.y};
        base2[2 * c + 1] = f32x2{e.z + f0.z, e.w + f0.w};
        f32x2 dflo       = f32x2{f1.x - f0.x, f1.y - f0.y};
        f32x2 dfhi       = f32x2{f1.z - f0.z, f1.w - f0.w};
        wv2[2 * c]       = f32x2{w.x, w.y};
        wv2[2 * c + 1]   = f32x2{w.z, w.w};
        dfw2[2 * c]      = dflo * wv2[2 * c];
        dfw2[2 * c + 1]  = dfhi * wv2[2 * c + 1];
        f32x2 alo = dflo * nk2;
        f32x2 ahi = dfhi * nk2;
        g2[2 * c].x     = EXP2F(alo.x);
        g2[2 * c].y     = EXP2F(alo.y);
        g2[2 * c + 1].x = EXP2F(ahi.x);
        g2[2 * c + 1].y = EXP2F(ahi.y);
    }

    float sA[8], sB[8];
#pragma unroll
    for (int b = 0; b < 8; ++b) { sA[b] = 0.f; sB[b] = 0.f; }

    const float* ccbase = Cc + (wave * 8) * 1024 + d0;
#pragma unroll
    for (int b = 0; b < 8; ++b) {
        const float4* q4 = reinterpret_cast<const float4*>(ccbase + b * 1024);
        float4 c0 = q4[0], c1 = q4[1], c2 = q4[2], c3 = q4[3];
        f32x2 cc2[8] = {f32x2{c0.x, c0.y}, f32x2{c0.z, c0.w},
                        f32x2{c1.x, c1.y}, f32x2{c1.z, c1.w},
                        f32x2{c2.x, c2.y}, f32x2{c2.z, c2.w},
                        f32x2{c3.x, c3.y}, f32x2{c3.z, c3.w}};
#pragma unroll
        for (int e = 0; e < 8; ++e) {
            f32x2 xa  = cc2[e] + base2[e];           // pk_add
            f32x2 arg = xa * nk2;                    // pk_mul
            f32x2 ta;
            ta.x = EXP2F(arg.x);
            ta.y = EXP2F(arg.y);
            f32x2 da  = ta + one2;                   // pk_add
            f32x2 db;                                // pk_fma: 1 + ta*g
            db.x = fmaf(ta.x, g2[e].x, 1.f);
            db.y = fmaf(ta.y, g2[e].y, 1.f);
            f32x2 xaw = xa * wv2[e];                 // pk_mul
            f32x2 xbw = xaw + dfw2[e];               // pk_add (xb eliminated)
            float numa = fmaf(xaw.x, da.y, xaw.y * da.x);
            float P = da.x * da.y;
            float numb = fmaf(xbw.x, db.y, xbw.y * db.x);
            float Q = db.x * db.y;
            float R = __builtin_amdgcn_rcpf(P * Q);
            sA[b] = fmaf(numa * Q, R, sA[b]);
            sB[b] = fmaf(numb * P, R, sB[b]);
        }
    }

    // 16-way merge reduction: final value index = (j = lane&1, b = (lane>>1)&7)
    bool p0 = lane & 1, p1 = lane & 2, p2 = lane & 4, p3 = lane & 8;
    float m[8];
#pragma unroll
    for (int k = 0; k < 8; ++k) {
        float keep = p0 ? sB[k] : sA[k];
        float send = p0 ? sA[k] : sB[k];
        m[k] = keep + __shfl_xor(send, 1, 64);
    }
    float n[4];
#pragma unroll
    for (int k = 0; k < 4; ++k) {
        float keep = p1 ? m[2 * k + 1] : m[2 * k];
        float send = p1 ? m[2 * k] : m[2 * k + 1];
        n[k] = keep + __shfl_xor(send, 2, 64);
    }
    float o2[2];
#pragma unroll
    for (int k = 0; k < 2; ++k) {
        float keep = p2 ? n[2 * k + 1] : n[2 * k];
        float send = p2 ? n[2 * k] : n[2 * k + 1];
        o2[k] = keep + __shfl_xor(send, 4, 64);
    }
    float F;
    {
        float keep = p3 ? o2[1] : o2[0];
        float send = p3 ? o2[0] : o2[1];
        F = keep + __shfl_xor(send, 8, 64);
    }
    F += __shfl_xor(F, 16, 64);
    F += __shfl_xor(F, 32, 64);

    // sigmoid wave-wide, then sum over b (lane bits 1..3)
    float sig = sigmoid_fast(F + b2[0]);
    sig += __shfl_xor(sig, 2, 64);
    sig += __shfl_xor(sig, 4, 64);
    sig += __shfl_xor(sig, 8, 64);

    __shared__ float red[4][2];
    if (lane < 2) red[wave][lane] = sig;
    __syncthreads();
    if (threadIdx.x < 2) {
        graph[i * 64 + j0 + threadIdx.x] =
            (red[0][threadIdx.x] + red[1][threadIdx.x] +
             red[2][threadIdx.x] + red[3][threadIdx.x]) * 0.03125f;
    }
}

extern "C" void kernel_launch(void* const* d_in, const int* in_sizes, int n_in,
                              void* d_out, int out_size, void* d_ws, size_t ws_size,
                              hipStream_t stream) {
    const float* obs     = (const float*)d_in[0];
    const float* action  = (const float*)d_in[1];
    const float* embed   = (const float*)d_in[2];
    const float* sc_w1   = (const float*)d_in[3];
    const float* sc_b1   = (const float*)d_in[4];
    const float* sc_w2   = (const float*)d_in[5];
    const float* sc_b2   = (const float*)d_in[6];
    const float* enc_w1  = (const float*)d_in[7];
    const float* enc_b1  = (const float*)d_in[8];
    const float* enc_w2  = (const float*)d_in[9];
    const float* enc_b2  = (const float*)d_in[10];
    const float* gru_wih = (const float*)d_in[11];
    const float* gru_bih = (const float*)d_in[13];
    const float* gru_bhh = (const float*)d_in[14];
    const float* dec_w   = (const float*)d_in[15];
    const float* dec_b   = (const float*)d_in[16];
    const float* rs_w1   = (const float*)d_in[17];
    const float* rs_b1   = (const float*)d_in[18];
    const float* rs_w2   = (const float*)d_in[19];
    const float* rs_b2   = (const float*)d_in[20];

    float* ws = (float*)d_ws;
    float* h1  = ws + 0;        // 32x1024
    float* z   = ws + 32768;    // 32x512
    float* gia = ws + 49152;    // 32x1536
    float* ha  = ws + 98304;    // 32x512
    float* r1  = ws + 114688;   // 32x512
    float* Cc  = ws + 131072;   // 32x1024
    float* Ea  = ws + 163840;   // 64x1024
    float* Eb  = ws + 229376;   // 64x1024

    float* h_out     = (float*)d_out;
    float* pred      = h_out + 16384;
    float* graph     = h_out + 40960;
    float* reasoning = h_out + 45056;

    front_kernel<<<1664, 256, 0, stream>>>(obs, enc_w1, enc_b1, h1,
                                           embed, sc_w1, sc_b1, Ea, Eb,
                                           action, gru_wih, gru_bih, gia);
    enc2_kernel<<<256, 256, 0, stream>>>(h1, enc_w2, enc_b2, z);
    gigru_kernel<<<1024, 256, 0, stream>>>(z, gru_wih, gia, gru_bhh, action, h_out, ha);
    mid_kernel<<<1152, 256, 0, stream>>>(h_out, ha, dec_w, dec_b, pred,
                                         rs_w1, rs_b1, r1, sc_w1, Cc);
    score_rs2_kernel<<<2048, 256, 0, stream>>>(Ea, Eb, Cc, sc_w2, sc_b2, graph,
                                               r1, rs_w2, rs_b2, reasoning);
}